// Round 5
// baseline (287.995 us; speedup 1.0000x reference)
//
#include <hip/hip_runtime.h>

#define NSUB   10000
#define NCLS   17
#define NG     500
#define NE     80000
#define HIDN   8
#define NEG_SLOPE 0.2f
#define NBLK   512

typedef __attribute__((ext_vector_type(8))) short short8;
typedef __attribute__((ext_vector_type(4))) float f32x4;

// ws layout (float units)
#define OFF_B1   0                        // 512x64 bf16 = 16384 float slots
#define OFF_B2   16384                    // 512x32 bf16 = 8192 float slots
#define OFF_D    (OFF_B2 + 8192)          // 32
#define OFF_XL   (OFF_D + 32)             // NSUB*8
#define OFF_XR   (OFF_XL + NSUB*HIDN)     // NSUB*8
#define OFF_LP   (OFF_XR + NSUB*HIDN)     // NSUB*17
#define OFF_E    (OFF_LP + NSUB*NCLS)     // NE
#define OFF_MORD (OFF_E + NE)             // NSUB (uint)
#define OFF_NUM  (OFF_MORD + NSUB)        // NSUB
#define OFF_DEN  (OFF_NUM + NSUB)         // NSUB
#define OFF_BAR  (OFF_DEN + NSUB + 16)    // 2 uints (cnt, gen), own line

__device__ __forceinline__ unsigned short f2bf(float f) {
    unsigned u = __float_as_uint(f);
    u += 0x7FFFu + ((u >> 16) & 1u);
    return (unsigned short)(u >> 16);
}
__device__ __forceinline__ unsigned f2ord(float f) {
    unsigned u = __float_as_uint(f);
    return (u & 0x80000000u) ? ~u : (u | 0x80000000u);
}
__device__ __forceinline__ float ord2f(unsigned o) {
    unsigned u = (o & 0x80000000u) ? (o ^ 0x80000000u) : ~o;
    return __uint_as_float(u);
}

#define MFMA16 __builtin_amdgcn_mfma_f32_16x16x32_bf16

// device-scope sense/generation grid barrier; bar[0]=cnt, bar[1]=gen (zeroed per launch)
__device__ __forceinline__ void gridbar(unsigned* bar) {
    __syncthreads();
    if (threadIdx.x == 0) {
        __threadfence();                                     // release prior writes
        unsigned g = __hip_atomic_load(bar + 1, __ATOMIC_RELAXED, __HIP_MEMORY_SCOPE_AGENT);
        unsigned a = __hip_atomic_fetch_add(bar, 1u, __ATOMIC_ACQ_REL, __HIP_MEMORY_SCOPE_AGENT);
        if (a == NBLK - 1) {
            __hip_atomic_store(bar, 0u, __ATOMIC_RELAXED, __HIP_MEMORY_SCOPE_AGENT);
            __hip_atomic_fetch_add(bar + 1, 1u, __ATOMIC_ACQ_REL, __HIP_MEMORY_SCOPE_AGENT);
        } else {
            while (__hip_atomic_load(bar + 1, __ATOMIC_RELAXED, __HIP_MEMORY_SCOPE_AGENT) == g)
                __builtin_amdgcn_s_sleep(2);
        }
        __threadfence();                                     // acquire
    }
    __syncthreads();
}

__device__ __forceinline__ void mk_frag(float4 v0, float4 v1, short8& a, short8& a2) {
    const float xv[8] = { v0.x, v0.y, v0.z, v0.w, v1.x, v1.y, v1.z, v1.w };
    #pragma unroll
    for (int e = 0; e < 8; e++) {
        a[e]  = (short)f2bf(xv[e]);
        a2[e] = (short)f2bf(xv[e] * xv[e]);
    }
}

__launch_bounds__(256, 2)
__global__ void k_all(const float* __restrict__ x, const float* __restrict__ Mu,
                      const float* __restrict__ Var, const int* __restrict__ ei,
                      const int* __restrict__ sidx, const float* __restrict__ Wp,
                      const float* __restrict__ Sp, const float* __restrict__ Wl,
                      const float* __restrict__ blv, const float* __restrict__ Wr,
                      const float* __restrict__ brv, const float* __restrict__ att,
                      float* __restrict__ out, float* __restrict__ ws) {
    unsigned short* B1 = (unsigned short*)(ws + OFF_B1);
    unsigned short* B2 = (unsigned short*)(ws + OFF_B2);
    float*    Dv   = ws + OFF_D;
    float*    XL   = ws + OFF_XL;
    float*    XR   = ws + OFF_XR;
    float*    LP   = ws + OFF_LP;
    float*    E    = ws + OFF_E;
    unsigned* MORD = (unsigned*)(ws + OFF_MORD);
    float*    NUM  = ws + OFF_NUM;
    float*    DEN  = ws + OFF_DEN;
    unsigned* bar  = (unsigned*)(ws + OFF_BAR);

    const int tid = threadIdx.x, b = blockIdx.x;
    const int w = tid >> 6, l = tid & 63;
    const int grp = l >> 4, j = l & 15;

    // ================= phase 0: prep =================
    if (b < 4) {
        // build B1/B2 bf16 fragments: t = kstep*64 + lane
        const int t = b * 256 + tid;
        const int ks = t >> 6, lane = t & 63;
        const int fgrp = lane >> 4, fj = lane & 15;
        unsigned short v1[4][8], v2[2][8];
        #pragma unroll
        for (int e = 0; e < 8; e++) {
            const int g = ks * 32 + fgrp * 8 + e;
            const bool gv = (g < NG);
            #pragma unroll
            for (int nt = 0; nt < 4; nt++) {
                const int col = nt * 16 + fj;
                float v = 0.f;
                if (gv) {
                    if (col >= 17 && col < 34)      v = Mu[(col - 17) * NG + g] / Var[(col - 17) * NG + g];
                    else if (col >= 34 && col < 42) v = Wl[g * HIDN + (col - 34)];
                    else if (col >= 42 && col < 50) v = Wr[g * HIDN + (col - 42)];
                }
                v1[nt][e] = f2bf(v);
            }
            #pragma unroll
            for (int nt = 0; nt < 2; nt++) {
                const int col = nt * 16 + fj;
                float v = 0.f;
                if (gv && col < NCLS) v = 1.0f / Var[col * NG + g];
                v2[nt][e] = f2bf(v);
            }
        }
        #pragma unroll
        for (int nt = 0; nt < 4; nt++)
            *reinterpret_cast<short8*>(B1 + (size_t)((ks * 4 + nt) * 64 + lane) * 8) =
                *reinterpret_cast<short8*>(v1[nt]);
        #pragma unroll
        for (int nt = 0; nt < 2; nt++)
            *reinterpret_cast<short8*>(B2 + (size_t)((ks * 2 + nt) * 64 + lane) * 8) =
                *reinterpret_cast<short8*>(v2[nt]);
    } else if (b < 21) {
        const int c = b - 4;
        float s = 0.f;
        for (int g = tid; g < NG; g += 256) {
            const float m = Mu[c * NG + g];
            s += m * m / Var[c * NG + g];
        }
        __shared__ float red[4];
        #pragma unroll
        for (int o = 32; o; o >>= 1) s += __shfl_xor(s, o);
        if (l == 0) red[w] = s;
        __syncthreads();
        if (tid == 0) Dv[c] = red[0] + red[1] + red[2] + red[3];
    } else if (b < 139) {
        const int i = (b - 21) * 256 + tid;          // zero MORD/NUM/DEN (30000 floats)
        if (i < 3 * NSUB) (ws + OFF_MORD)[i] = 0.f;
    } else if (b == 139) {
        if (tid < 2) out[tid] = 0.f;
    }

    gridbar(bar);

    // ================= phase 1: MFMA GEMM (K split across wave pairs) =================
    {
        __shared__ float ct[4][16][68];
        const int pid  = b * 2 + (w >> 1);           // pair id = tile id (625 tiles, 16 rows each)
        const int half = w & 1;                      // half 0: ks 0..7, half 1: ks 8..15
        const bool act = (pid < 625);

        if (act) {
            const int rowbase = pid * 16;
            const float* xr = x + (size_t)(rowbase + j) * NG;
            const short8* b1 = reinterpret_cast<const short8*>(B1);
            const short8* b2 = reinterpret_cast<const short8*>(B2);
            f32x4 a0 = {0,0,0,0}, a1 = {0,0,0,0}, a2c = {0,0,0,0}, a3 = {0,0,0,0};

            if (half == 0) {
                #pragma unroll 2
                for (int ks = 0; ks < 8; ks++) {
                    const int g0 = ks * 32 + grp * 8;
                    short8 fa, fa2;
                    mk_frag(*reinterpret_cast<const float4*>(xr + g0),
                            *reinterpret_cast<const float4*>(xr + g0 + 4), fa, fa2);
                    const short8* p1 = b1 + (size_t)(ks * 4) * 64 + l;
                    const short8* p2 = b2 + (size_t)(ks * 2) * 64 + l;
                    a0  = MFMA16(fa,  p1[0],   a0,  0, 0, 0);
                    a1  = MFMA16(fa,  p1[64],  a1,  0, 0, 0);
                    a2c = MFMA16(fa,  p1[128], a2c, 0, 0, 0);
                    a3  = MFMA16(fa,  p1[192], a3,  0, 0, 0);
                    a0  = MFMA16(fa2, p2[0],   a0,  0, 0, 0);
                    a1  = MFMA16(fa2, p2[64],  a1,  0, 0, 0);
                }
            } else {
                #pragma unroll 2
                for (int ks = 8; ks < 15; ks++) {
                    const int g0 = ks * 32 + grp * 8;
                    short8 fa, fa2;
                    mk_frag(*reinterpret_cast<const float4*>(xr + g0),
                            *reinterpret_cast<const float4*>(xr + g0 + 4), fa, fa2);
                    const short8* p1 = b1 + (size_t)(ks * 4) * 64 + l;
                    const short8* p2 = b2 + (size_t)(ks * 2) * 64 + l;
                    a0  = MFMA16(fa,  p1[0],   a0,  0, 0, 0);
                    a1  = MFMA16(fa,  p1[64],  a1,  0, 0, 0);
                    a2c = MFMA16(fa,  p1[128], a2c, 0, 0, 0);
                    a3  = MFMA16(fa,  p1[192], a3,  0, 0, 0);
                    a0  = MFMA16(fa2, p2[0],   a0,  0, 0, 0);
                    a1  = MFMA16(fa2, p2[64],  a1,  0, 0, 0);
                }
                {   // ks = 15 tail: genes 480..499 valid
                    const int g0 = 480 + grp * 8;
                    float4 v0 = {0,0,0,0}, v1 = {0,0,0,0};
                    if (g0 <= 496) v0 = *reinterpret_cast<const float4*>(xr + g0);
                    if (g0 <= 488) v1 = *reinterpret_cast<const float4*>(xr + g0 + 4);
                    short8 fa, fa2;
                    mk_frag(v0, v1, fa, fa2);
                    const short8* p1 = b1 + (size_t)(15 * 4) * 64 + l;
                    const short8* p2 = b2 + (size_t)(15 * 2) * 64 + l;
                    a0  = MFMA16(fa,  p1[0],   a0,  0, 0, 0);
                    a1  = MFMA16(fa,  p1[64],  a1,  0, 0, 0);
                    a2c = MFMA16(fa,  p1[128], a2c, 0, 0, 0);
                    a3  = MFMA16(fa,  p1[192], a3,  0, 0, 0);
                    a0  = MFMA16(fa2, p2[0],   a0,  0, 0, 0);
                    a1  = MFMA16(fa2, p2[64],  a1,  0, 0, 0);
                }
            }
            // C layout: row = grp*4 + r, col = nt*16 + j
            #pragma unroll
            for (int r = 0; r < 4; r++) {
                ct[w][grp * 4 + r][j]      = a0[r];
                ct[w][grp * 4 + r][16 + j] = a1[r];
                ct[w][grp * 4 + r][32 + j] = a2c[r];
                ct[w][grp * 4 + r][48 + j] = a3[r];
            }
        }
        __syncthreads();

        float ll = 0.f;
        if (act && (w & 1) == 0 && l < 16) {
            const int cell = pid * 16 + l;
            const float* c0 = &ct[w][l][0];
            const float* c1 = &ct[w + 1][l][0];
            const int idx = sidx[cell];
            const float* wrow = Wp + (size_t)idx * NCLS;
            float p[NCLS];
            float mx = -1e30f;
            #pragma unroll
            for (int c = 0; c < NCLS; c++) { p[c] = wrow[c]; mx = fmaxf(mx, p[c]); }
            float sum = 0.f;
            #pragma unroll
            for (int c = 0; c < NCLS; c++) { p[c] = __expf(p[c] - mx); sum += p[c]; }
            const float inv = 1.0f / sum;
            const float s = Sp[idx];
            float* orow = out + 2 + (size_t)cell * NCLS;
            float* lrow = LP + (size_t)cell * NCLS;
            #pragma unroll
            for (int c = 0; c < NCLS; c++) {
                p[c] *= inv;
                orow[c] = p[c];
                lrow[c] = __logf(p[c] + 1e-8f);
                const float T1 = c0[c] + c1[c];
                const float T2 = c0[NCLS + c] + c1[NCLS + c];
                ll += p[c] * (-0.5f * T1 + s * T2 - 0.5f * s * s * Dv[c]);
            }
            #pragma unroll
            for (int h = 0; h < HIDN; h++) {
                XL[cell * HIDN + h] = c0[34 + h] + c1[34 + h] + blv[h];
                XR[cell * HIDN + h] = c0[42 + h] + c1[42 + h] + brv[h];
            }
        }
        if (act && (w & 1) == 0) {
            #pragma unroll
            for (int o = 32; o; o >>= 1) ll += __shfl_xor(ll, o);
            if (l == 0) atomicAdd(out, ll * (1.0f / NSUB));
        }
    }

    gridbar(bar);

    // ================= phase 2: edge e_k + segment max =================
    const int gid = b * 256 + tid;
    if (gid < NE) {
        const int s = ei[gid], d = ei[NE + gid];
        const float4 xa0 = *reinterpret_cast<const float4*>(XL + s * HIDN);
        const float4 xa1 = *reinterpret_cast<const float4*>(XL + s * HIDN + 4);
        const float4 xb0 = *reinterpret_cast<const float4*>(XR + d * HIDN);
        const float4 xb1 = *reinterpret_cast<const float4*>(XR + d * HIDN + 4);
        float hv[8] = { xa0.x + xb0.x, xa0.y + xb0.y, xa0.z + xb0.z, xa0.w + xb0.w,
                        xa1.x + xb1.x, xa1.y + xb1.y, xa1.z + xb1.z, xa1.w + xb1.w };
        float e = 0.f;
        #pragma unroll
        for (int h = 0; h < HIDN; h++) {
            float v = hv[h];
            v = (v > 0.f) ? v : NEG_SLOPE * v;
            e += v * att[h];
        }
        E[gid] = e;
        atomicMax(MORD + d, f2ord(e));
    }

    gridbar(bar);

    // ================= phase 3: exp + weighted accumulation =================
    if (gid < NE) {
        const int s = ei[gid], d = ei[NE + gid];
        const float m = ord2f(MORD[d]);
        const float ex = __expf(E[gid] - m);
        const float* Ps = out + 2 + (size_t)s * NCLS;
        const float* Ld = LP + (size_t)d * NCLS;
        float wgt = 0.f;
        #pragma unroll
        for (int c = 0; c < NCLS; c++) wgt += Ps[c] * Ld[c];
        atomicAdd(NUM + d, ex * wgt);
        atomicAdd(DEN + d, ex);
    }

    gridbar(bar);

    // ================= phase 4: node reduce =================
    {
        float v = 0.f;
        if (gid < NSUB) {
            const float dd = DEN[gid];
            if (dd > 0.f) v = NUM[gid] / dd;
        }
        #pragma unroll
        for (int o = 32; o; o >>= 1) v += __shfl_xor(v, o);
        if (l == 0 && v != 0.f) atomicAdd(out + 1, -v * (1.0f / NSUB));
    }
}

extern "C" void kernel_launch(void* const* d_in, const int* in_sizes, int n_in,
                              void* d_out, int out_size, void* d_ws, size_t ws_size,
                              hipStream_t stream) {
    const float* x    = (const float*)d_in[0];
    const float* Mu   = (const float*)d_in[1];
    const float* Var  = (const float*)d_in[2];
    const int*   ei   = (const int*)d_in[3];
    const int*   sidx = (const int*)d_in[4];
    const float* Wp   = (const float*)d_in[5];
    const float* Sp   = (const float*)d_in[6];
    const float* Wl   = (const float*)d_in[7];
    const float* bl   = (const float*)d_in[8];
    const float* Wr   = (const float*)d_in[9];
    const float* br   = (const float*)d_in[10];
    const float* att  = (const float*)d_in[11];
    float* out = (float*)d_out;
    float* ws  = (float*)d_ws;

    (void)in_sizes; (void)n_in; (void)out_size; (void)ws_size;

    hipMemsetAsync(ws + OFF_BAR, 0, 2 * sizeof(unsigned), stream);
    k_all<<<NBLK, 256, 0, stream>>>(x, Mu, Var, ei, sidx, Wp, Sp, Wl, bl, Wr, br, att,
                                    out, ws);
}

// Round 6
// 46.690 us; speedup vs baseline: 6.1682x; 6.1682x over previous
//
#include <hip/hip_runtime.h>

#define NSUB   10000
#define NCLS   17
#define NG     500
#define NE     80000
#define HIDN   8
#define NEG_SLOPE 0.2f

typedef __attribute__((ext_vector_type(8))) short short8;
typedef __attribute__((ext_vector_type(4))) float f32x4;

// ws layout (float units)
#define OFF_B1   0                        // 512x64 bf16 = 16384 float slots
#define OFF_B2   16384                    // 512x32 bf16 = 8192 float slots
#define OFF_D    (OFF_B2 + 8192)          // 32
#define OFF_XL   (OFF_D + 32)             // NSUB*8
#define OFF_XR   (OFF_XL + NSUB*HIDN)     // NSUB*8
#define OFF_PP   (OFF_XR + NSUB*HIDN)     // NSUB*20 (P padded, pad=0)
#define OFF_LL   (OFF_PP + NSUB*20)       // NSUB*20 (logP padded, pad=0)
#define OFF_NUM  (OFF_LL + NSUB*20)       // NSUB
#define OFF_DEN  (OFF_NUM + NSUB)         // NSUB

__device__ __forceinline__ unsigned short f2bf(float f) {
    unsigned u = __float_as_uint(f);
    u += 0x7FFFu + ((u >> 16) & 1u);      // round-to-nearest-even
    return (unsigned short)(u >> 16);
}

#define MFMA16 __builtin_amdgcn_mfma_f32_16x16x32_bf16

// ---- prep: B1/B2 bf16 fragments, D[c], zero out[0..1] + NUM/DEN ----
// B1[k][n] n: 17..33 Mu/Var | 34..41 Wl | 42..49 Wr | else 0.  B2[k][n] n<17: 1/Var.
// Fragment: lane holds col=(lane&15)+nt*16, k = ks*32 + (lane>>4)*8 + e.
__global__ void k_prep(const float* __restrict__ Mu, const float* __restrict__ Var,
                       const float* __restrict__ Wl, const float* __restrict__ Wr,
                       unsigned short* __restrict__ B1, unsigned short* __restrict__ B2,
                       float* __restrict__ D, float* __restrict__ zeroBase,
                       float* __restrict__ out) {
    const int b = blockIdx.x;
    if (b < 4) {
        const int t = b * 256 + threadIdx.x;        // 1024 threads = 16 ksteps * 64 lanes
        const int ks = t >> 6, lane = t & 63;
        const int fgrp = lane >> 4, fj = lane & 15;
        unsigned short v1[4][8], v2[2][8];
        #pragma unroll
        for (int e = 0; e < 8; e++) {
            const int g = ks * 32 + fgrp * 8 + e;
            const bool gv = (g < NG);
            #pragma unroll
            for (int nt = 0; nt < 4; nt++) {
                const int col = nt * 16 + fj;
                float v = 0.f;
                if (gv) {
                    if (col >= 17 && col < 34)      v = Mu[(col - 17) * NG + g] / Var[(col - 17) * NG + g];
                    else if (col >= 34 && col < 42) v = Wl[g * HIDN + (col - 34)];
                    else if (col >= 42 && col < 50) v = Wr[g * HIDN + (col - 42)];
                }
                v1[nt][e] = f2bf(v);
            }
            #pragma unroll
            for (int nt = 0; nt < 2; nt++) {
                const int col = nt * 16 + fj;
                float v = 0.f;
                if (gv && col < NCLS) v = 1.0f / Var[col * NG + g];
                v2[nt][e] = f2bf(v);
            }
        }
        #pragma unroll
        for (int nt = 0; nt < 4; nt++)
            *reinterpret_cast<short8*>(B1 + (size_t)((ks * 4 + nt) * 64 + lane) * 8) =
                *reinterpret_cast<short8*>(v1[nt]);
        #pragma unroll
        for (int nt = 0; nt < 2; nt++)
            *reinterpret_cast<short8*>(B2 + (size_t)((ks * 2 + nt) * 64 + lane) * 8) =
                *reinterpret_cast<short8*>(v2[nt]);
    } else if (b < 21) {
        const int c = b - 4;
        float s = 0.f;
        for (int g = threadIdx.x; g < NG; g += 256) {
            const float m = Mu[c * NG + g];
            s += m * m / Var[c * NG + g];
        }
        __shared__ float red[4];
        #pragma unroll
        for (int o = 32; o; o >>= 1) s += __shfl_xor(s, o);
        const int w = threadIdx.x >> 6, l = threadIdx.x & 63;
        if (l == 0) red[w] = s;
        __syncthreads();
        if (threadIdx.x == 0) D[c] = red[0] + red[1] + red[2] + red[3];
    } else {
        const int i = (b - 21) * 256 + threadIdx.x;   // zero NUM/DEN (2*NSUB floats)
        if (i < 2 * NSUB) zeroBase[i] = 0.f;
        if (b == 21 && threadIdx.x < 2) out[threadIdx.x] = 0.f;
    }
}

// ---- per-cell: MFMA GEMM, 1 tile (16 cells) per block, K split across 4 waves ----
__launch_bounds__(256)
__global__ void k_cell(const float* __restrict__ x, const int* __restrict__ sidx,
                       const float* __restrict__ Wp, const float* __restrict__ Sp,
                       const float* __restrict__ blv, const float* __restrict__ brv,
                       const unsigned short* __restrict__ B1,
                       const unsigned short* __restrict__ B2,
                       const float* __restrict__ D,
                       float* __restrict__ out, float* __restrict__ XL,
                       float* __restrict__ XR, float* __restrict__ PP,
                       float* __restrict__ LL) {
    const int tid = threadIdx.x;
    const int w = tid >> 6, l = tid & 63;
    const int grp = l >> 4, j = l & 15;
    const int rowbase = blockIdx.x * 16;             // 625 tiles exactly, no bounds checks

    f32x4 a0 = {0,0,0,0}, a1 = {0,0,0,0}, a2 = {0,0,0,0}, a3 = {0,0,0,0};
    const float* xr = x + (size_t)(rowbase + j) * NG;
    const short8* b1 = reinterpret_cast<const short8*>(B1);
    const short8* b2 = reinterpret_cast<const short8*>(B2);

#define KSTEP(ks, fa, fa2)                                               \
    {                                                                    \
        const short8* p1 = b1 + (size_t)((ks) * 4) * 64 + l;             \
        const short8* p2 = b2 + (size_t)((ks) * 2) * 64 + l;             \
        a0 = MFMA16(fa,  p1[0],   a0, 0, 0, 0);                          \
        a1 = MFMA16(fa,  p1[64],  a1, 0, 0, 0);                          \
        a2 = MFMA16(fa,  p1[128], a2, 0, 0, 0);                          \
        a3 = MFMA16(fa,  p1[192], a3, 0, 0, 0);                          \
        a0 = MFMA16(fa2, p2[0],   a0, 0, 0, 0);                          \
        a1 = MFMA16(fa2, p2[64],  a1, 0, 0, 0);                          \
    }

    const int ks0 = w * 4;
    // 3 full K-steps for every wave
    #pragma unroll
    for (int i = 0; i < 3; i++) {
        const int ks = ks0 + i;
        const int g0 = ks * 32 + grp * 8;
        const float4 v0 = *reinterpret_cast<const float4*>(xr + g0);
        const float4 v1 = *reinterpret_cast<const float4*>(xr + g0 + 4);
        const float xv[8] = { v0.x, v0.y, v0.z, v0.w, v1.x, v1.y, v1.z, v1.w };
        short8 fa, fa2;
        #pragma unroll
        for (int e = 0; e < 8; e++) { fa[e] = (short)f2bf(xv[e]); fa2[e] = (short)f2bf(xv[e] * xv[e]); }
        KSTEP(ks, fa, fa2);
    }
    if (w < 3) {                                     // 4th full K-step
        const int ks = ks0 + 3;
        const int g0 = ks * 32 + grp * 8;
        const float4 v0 = *reinterpret_cast<const float4*>(xr + g0);
        const float4 v1 = *reinterpret_cast<const float4*>(xr + g0 + 4);
        const float xv[8] = { v0.x, v0.y, v0.z, v0.w, v1.x, v1.y, v1.z, v1.w };
        short8 fa, fa2;
        #pragma unroll
        for (int e = 0; e < 8; e++) { fa[e] = (short)f2bf(xv[e]); fa2[e] = (short)f2bf(xv[e] * xv[e]); }
        KSTEP(ks, fa, fa2);
    } else {                                         // ks = 15 tail: genes 480..499 valid
        const int g0 = 480 + grp * 8;
        float4 v0 = {0,0,0,0}, v1 = {0,0,0,0};
        if (g0 <= 496) v0 = *reinterpret_cast<const float4*>(xr + g0);
        if (g0 <= 488) v1 = *reinterpret_cast<const float4*>(xr + g0 + 4);
        const float xv[8] = { v0.x, v0.y, v0.z, v0.w, v1.x, v1.y, v1.z, v1.w };
        short8 fa, fa2;
        #pragma unroll
        for (int e = 0; e < 8; e++) { fa[e] = (short)f2bf(xv[e]); fa2[e] = (short)f2bf(xv[e] * xv[e]); }
        KSTEP(15, fa, fa2);
    }
#undef KSTEP

    // C layout: row = grp*4 + r, col = nt*16 + j (m89-verified)
    __shared__ float ct[4][16][68];
    #pragma unroll
    for (int r = 0; r < 4; r++) {
        ct[w][grp * 4 + r][j]      = a0[r];
        ct[w][grp * 4 + r][16 + j] = a1[r];
        ct[w][grp * 4 + r][32 + j] = a2[r];
        ct[w][grp * 4 + r][48 + j] = a3[r];
    }
    __syncthreads();

    if (w == 0) {
        float ll = 0.f;
        if (l < 16) {
            const int cell = rowbase + l;
            const int idx = sidx[cell];
            const float* wrow = Wp + (size_t)idx * NCLS;
            float p[NCLS];
            float mx = -1e30f;
            #pragma unroll
            for (int c = 0; c < NCLS; c++) { p[c] = wrow[c]; mx = fmaxf(mx, p[c]); }
            float sum = 0.f;
            #pragma unroll
            for (int c = 0; c < NCLS; c++) { p[c] = __expf(p[c] - mx); sum += p[c]; }
            const float inv = 1.0f / sum;
            const float s = Sp[idx];
            float* orow = out + 2 + (size_t)cell * NCLS;
            float* prow = PP + (size_t)cell * 20;
            float* lrow = LL + (size_t)cell * 20;
            #pragma unroll
            for (int c = 0; c < NCLS; c++) {
                p[c] *= inv;
                const float lg = __logf(p[c] + 1e-8f);
                orow[c] = p[c];
                prow[c] = p[c];
                lrow[c] = lg;
                const float T1 = ct[0][l][c] + ct[1][l][c] + ct[2][l][c] + ct[3][l][c];
                const float T2 = ct[0][l][NCLS + c] + ct[1][l][NCLS + c]
                               + ct[2][l][NCLS + c] + ct[3][l][NCLS + c];
                ll += p[c] * (-0.5f * T1 + s * T2 - 0.5f * s * s * D[c]);
            }
            prow[17] = 0.f; prow[18] = 0.f; prow[19] = 0.f;
            lrow[17] = 0.f; lrow[18] = 0.f; lrow[19] = 0.f;
            #pragma unroll
            for (int h = 0; h < HIDN; h++) {
                XL[cell * HIDN + h] = ct[0][l][34 + h] + ct[1][l][34 + h]
                                    + ct[2][l][34 + h] + ct[3][l][34 + h] + blv[h];
                XR[cell * HIDN + h] = ct[0][l][42 + h] + ct[1][l][42 + h]
                                    + ct[2][l][42 + h] + ct[3][l][42 + h] + brv[h];
            }
        }
        #pragma unroll
        for (int o = 32; o; o >>= 1) ll += __shfl_xor(ll, o);
        if (l == 0) atomicAdd(out, ll * (1.0f / NSUB));
    }
}

// ---- fused edge pass: e -> exp(e) (no max shift; |e| ~ O(7)) + NUM/DEN atomics ----
__global__ void k_edge(const int* __restrict__ ei, const float* __restrict__ XL,
                       const float* __restrict__ XR, const float* __restrict__ att,
                       const float* __restrict__ PP, const float* __restrict__ LL,
                       float* __restrict__ NUM, float* __restrict__ DEN) {
    const int k = blockIdx.x * 256 + threadIdx.x;
    if (k >= NE) return;
    const int s = ei[k], d = ei[NE + k];
    const float4 xa0 = *reinterpret_cast<const float4*>(XL + s * HIDN);
    const float4 xa1 = *reinterpret_cast<const float4*>(XL + s * HIDN + 4);
    const float4 xb0 = *reinterpret_cast<const float4*>(XR + d * HIDN);
    const float4 xb1 = *reinterpret_cast<const float4*>(XR + d * HIDN + 4);
    const float hv[8] = { xa0.x + xb0.x, xa0.y + xb0.y, xa0.z + xb0.z, xa0.w + xb0.w,
                          xa1.x + xb1.x, xa1.y + xb1.y, xa1.z + xb1.z, xa1.w + xb1.w };
    float e = 0.f;
    #pragma unroll
    for (int h = 0; h < HIDN; h++) {
        const float v = hv[h];
        e += ((v > 0.f) ? v : NEG_SLOPE * v) * att[h];
    }
    const float ex = __expf(e);
    float wgt = 0.f;
    #pragma unroll
    for (int q = 0; q < 5; q++) {
        const float4 ps = *reinterpret_cast<const float4*>(PP + (size_t)s * 20 + q * 4);
        const float4 ld = *reinterpret_cast<const float4*>(LL + (size_t)d * 20 + q * 4);
        wgt += ps.x * ld.x + ps.y * ld.y + ps.z * ld.z + ps.w * ld.w;
    }
    atomicAdd(NUM + d, ex * wgt);
    atomicAdd(DEN + d, ex);
}

// ---- node pass: ce_space = -sum(num/den)/n ----
__global__ void k_node(const float* __restrict__ NUM, const float* __restrict__ DEN,
                       float* __restrict__ out) {
    const int n = blockIdx.x * 256 + threadIdx.x;
    float v = 0.f;
    if (n < NSUB) {
        const float dd = DEN[n];
        if (dd > 0.f) v = NUM[n] / dd;
    }
    #pragma unroll
    for (int o = 32; o; o >>= 1) v += __shfl_xor(v, o);
    if ((threadIdx.x & 63) == 0 && v != 0.f) atomicAdd(out + 1, -v * (1.0f / NSUB));
}

extern "C" void kernel_launch(void* const* d_in, const int* in_sizes, int n_in,
                              void* d_out, int out_size, void* d_ws, size_t ws_size,
                              hipStream_t stream) {
    const float* x    = (const float*)d_in[0];
    const float* Mu   = (const float*)d_in[1];
    const float* Var  = (const float*)d_in[2];
    const int*   ei   = (const int*)d_in[3];
    const int*   sidx = (const int*)d_in[4];
    const float* Wp   = (const float*)d_in[5];
    const float* Sp   = (const float*)d_in[6];
    const float* Wl   = (const float*)d_in[7];
    const float* bl   = (const float*)d_in[8];
    const float* Wr   = (const float*)d_in[9];
    const float* br   = (const float*)d_in[10];
    const float* att  = (const float*)d_in[11];
    float* out = (float*)d_out;
    float* ws  = (float*)d_ws;

    unsigned short* B1 = (unsigned short*)(ws + OFF_B1);
    unsigned short* B2 = (unsigned short*)(ws + OFF_B2);
    float* D   = ws + OFF_D;
    float* XL  = ws + OFF_XL;
    float* XR  = ws + OFF_XR;
    float* PP  = ws + OFF_PP;
    float* LL  = ws + OFF_LL;
    float* NUM = ws + OFF_NUM;
    float* DEN = ws + OFF_DEN;

    (void)in_sizes; (void)n_in; (void)out_size; (void)ws_size;

    // 4 (frag) + 17 (D) + 79 (zero NUM/DEN + out[0..1])
    k_prep<<<100, 256, 0, stream>>>(Mu, Var, Wl, Wr, B1, B2, D, NUM, out);
    k_cell<<<NSUB / 16, 256, 0, stream>>>(x, sidx, Wp, Sp, bl, br, B1, B2, D,
                                          out, XL, XR, PP, LL);
    k_edge<<<(NE + 255) / 256, 256, 0, stream>>>(ei, XL, XR, att, PP, LL, NUM, DEN);
    k_node<<<(NSUB + 255) / 256, 256, 0, stream>>>(NUM, DEN, out);
}